// Round 10
// baseline (224.983 us; speedup 1.0000x reference)
//
#include <hip/hip_runtime.h>
#include <hip/hip_bf16.h>

typedef unsigned short u16;
typedef __attribute__((ext_vector_type(4))) float f32x4;
typedef __attribute__((ext_vector_type(8))) __bf16 bf16x8;
typedef __attribute__((ext_vector_type(8))) short short8;
typedef __attribute__((ext_vector_type(4))) short s16x4;

constexpr int SEQ = 8192;
constexpr int DM  = 512;
constexpr int HD  = 64;
constexpr int HFF = 2048;

__device__ __forceinline__ float b2f(u16 u){
  union { unsigned int i; float f; } v; v.i = ((unsigned int)u) << 16; return v.f;
}
__device__ __forceinline__ u16 f2b(float f){
  union { float f; unsigned int i; } v; v.f = f;
  unsigned int r = v.i + 0x7FFFu + ((v.i >> 16) & 1u);
  return (u16)(r >> 16);
}

// async global->LDS, 16B per lane; LDS base must be wave-uniform.
__device__ __forceinline__ void gload16(const u16* g, u16* lds){
  __builtin_amdgcn_global_load_lds(
      (const __attribute__((address_space(1))) void*)g,
      (__attribute__((address_space(3))) void*)lds, 16, 0, 0);
}

// ------- fused: out0 = enc (fp32 passthrough), enc_b = bf16(enc) ----------
__global__ __launch_bounds__(256) void copycvt_k(const float* __restrict__ in,
                                                 float* __restrict__ outf,
                                                 u16* __restrict__ outb, long n8){
  long i = blockIdx.x * 256L + threadIdx.x;
  if(i >= n8) return;
  f32x4 a = ((const f32x4*)in)[i*2];
  f32x4 b = ((const f32x4*)in)[i*2+1];
  ((f32x4*)outf)[i*2]   = a;
  ((f32x4*)outf)[i*2+1] = b;
  u16 ov[8];
  for(int j=0;j<4;j++){ ov[j] = f2b(a[j]); ov[4+j] = f2b(b[j]); }
  ((short8*)outb)[i] = *(short8*)ov;
}

__global__ __launch_bounds__(256) void cvt_k(const float* __restrict__ in,
                                             u16* __restrict__ out, long n8){
  long i = blockIdx.x * 256L + threadIdx.x;
  if(i >= n8) return;
  f32x4 a = ((const f32x4*)in)[i*2];
  f32x4 b = ((const f32x4*)in)[i*2+1];
  u16 ov[8];
  for(int j=0;j<4;j++){ ov[j] = f2b(a[j]); ov[4+j] = f2b(b[j]); }
  ((short8*)out)[i] = *(short8*)ov;
}

// ------- batched transpose of the six [512,64] projection weights --------
__global__ __launch_bounds__(256) void wtrans6_k(const float* __restrict__ w0,
                                                 const float* __restrict__ w1,
                                                 const float* __restrict__ w2,
                                                 const float* __restrict__ w3,
                                                 const float* __restrict__ w4,
                                                 const float* __restrict__ w5,
                                                 u16* __restrict__ out){
  __shared__ u16 t[32][33];
  const float* ins[6] = {w0,w1,w2,w3,w4,w5};
  const float* in = ins[blockIdx.z];
  u16* o = out + (long)blockIdx.z * 32768;
  int c0 = blockIdx.x*32, r0 = blockIdx.y*32;
  int tx = threadIdx.x, ty = threadIdx.y;     // blockDim (32,8)
  for(int i=0;i<4;i++)
    t[ty+i*8][tx] = f2b(in[(long)(r0+ty+i*8)*HD + c0+tx]);
  __syncthreads();
  for(int i=0;i<4;i++) o[(long)(c0+ty+i*8)*DM + r0+tx] = t[tx][ty+i*8];
}

// ---------------- generic 32x32 transpose; IN_F: 1=fp32 in, 0=bf16 in ----
template<int IN_F>
__global__ __launch_bounds__(256) void transpose_k(const void* __restrict__ inp,
                                                   u16* __restrict__ out, int R, int C){
  __shared__ u16 t[32][33];
  int c0 = blockIdx.x*32, r0 = blockIdx.y*32;
  int tx = threadIdx.x, ty = threadIdx.y;     // blockDim (32,8)
  for(int i=0;i<4;i++){
    long idx = (long)(r0+ty+i*8)*C + c0+tx;
    u16 v;
    if constexpr (IN_F) v = f2b(((const float*)inp)[idx]);
    else                v = ((const u16*)inp)[idx];
    t[ty+i*8][tx] = v;
  }
  __syncthreads();
  for(int i=0;i<4;i++) out[(long)(c0+ty+i*8)*R + r0+tx] = t[tx][ty+i*8];
}

// ------- batched transpose of two [8192,64] V matrices -> [64,8192] ------
__global__ __launch_bounds__(256) void vtrans2_k(const u16* __restrict__ v0,
                                                 u16* __restrict__ o0,
                                                 const u16* __restrict__ v1,
                                                 u16* __restrict__ o1){
  __shared__ u16 t[32][33];
  const u16* in = blockIdx.z ? v1 : v0;
  u16* o = blockIdx.z ? o1 : o0;
  int c0 = blockIdx.x*32, r0 = blockIdx.y*32;
  int tx = threadIdx.x, ty = threadIdx.y;
  for(int i=0;i<4;i++) t[ty+i*8][tx] = in[(long)(r0+ty+i*8)*HD + c0+tx];
  __syncthreads();
  for(int i=0;i<4;i++) o[(long)(c0+ty+i*8)*SEQ + r0+tx] = t[tx][ty+i*8];
}

// ---------------- w_o head-sum, transposed ----------------
__global__ __launch_bounds__(256) void wosum_k(const float* __restrict__ wo,
                                               u16* __restrict__ outT){
  int tid = blockIdx.x*256 + threadIdx.x;     // 32768 total
  int n = tid >> 6, p = tid & 63;
  float s = 0.f;
  for(int h=0; h<8; h++) s += wo[(long)(h*64+p)*DM + n];
  outT[n*64+p] = f2b(s);
}

// ---------------- fused residual-add + LayerNorm ----------------
template<bool WRITE_BF>
__global__ __launch_bounds__(256) void add_ln(const u16* __restrict__ Xa,
                                              const float* __restrict__ Xb,
                                              const float* __restrict__ G,
                                              const float* __restrict__ Bb,
                                              float* __restrict__ OutF,
                                              u16* __restrict__ OutB){
  int row  = blockIdx.x*4 + (threadIdx.x>>6);
  int lane = threadIdx.x & 63;
  short8 a8 = *(const short8*)&Xa[(long)row*DM + lane*8];
  f32x4 b0 = *(const f32x4*)&Xb[(long)row*DM + lane*8];
  f32x4 b1 = *(const f32x4*)&Xb[(long)row*DM + lane*8 + 4];
  float x[8]; float s=0.f, s2=0.f;
  for(int i=0;i<8;i++){
    float bv = (i<4) ? b0[i] : b1[i-4];
    x[i] = b2f((u16)a8[i]) + bv;
    s += x[i]; s2 += x[i]*x[i];
  }
  for(int o=1;o<64;o<<=1){ s += __shfl_xor(s,o); s2 += __shfl_xor(s2,o); }
  float mu  = s * (1.f/DM);
  float var = s2 * (1.f/DM) - mu*mu;
  float rstd = rsqrtf(var + 1e-5f);
  f32x4 g0 = *(const f32x4*)&G[lane*8];
  f32x4 g1 = *(const f32x4*)&G[lane*8+4];
  f32x4 p0 = *(const f32x4*)&Bb[lane*8];
  f32x4 p1 = *(const f32x4*)&Bb[lane*8+4];
  float of[8]; u16 ob[8];
  for(int i=0;i<8;i++){
    float gv = (i<4)?g0[i]:g1[i-4], bv2 = (i<4)?p0[i]:p1[i-4];
    float v = (x[i]-mu)*rstd*gv + bv2;
    of[i] = v; ob[i] = f2b(v);
  }
  *(f32x4*)&OutF[(long)row*DM + lane*8]     = *(f32x4*)&of[0];
  *(f32x4*)&OutF[(long)row*DM + lane*8 + 4] = *(f32x4*)&of[4];
  if constexpr (WRITE_BF)
    *(short8*)&OutB[(long)row*DM + lane*8] = *(short8*)ob;
}

// ---- GEMM v2: global_load_lds staging, source-swizzled LDS.
// DBUF=true: double-buffered stage-early. DBUF=false: single-buffer (m97).
template<int BM,int BN,int EPI,bool DBUF>
__global__ __launch_bounds__(256) void gemm2(const u16* __restrict__ A,
                                             const u16* __restrict__ Bt,
                                             u16* __restrict__ C,
                                             const float* __restrict__ bias,
                                             int N, int K, long sB, long sC){
  constexpr int WR=2, WC=2;
  constexpr int WM = BM/WR, WN = BN/WC;
  constexpr int MF = WM/16, NF = WN/16;
  constexpr int NB = DBUF ? 2 : 1;
  __shared__ u16 As[NB][BM*64];
  __shared__ u16 Bs[NB][BN*64];

  const int tid = threadIdx.x;
  const int wid = tid >> 6, lane = tid & 63;
  const int g = lane >> 4, lr = lane & 15;
  const int m0 = blockIdx.x * BM;
  const int n0 = blockIdx.y * BN;
  Bt += (long)blockIdx.z * sB;
  C  += (long)blockIdx.z * sC;
  const int wr = wid / WC, wc = wid % WC;

  f32x4 acc[MF][NF];
  for(int m=0;m<MF;m++) for(int n=0;n<NF;n++) acc[m][n] = (f32x4)0.f;

  auto stage = [&](const u16* src, int base_row, u16* lds, int rows, int k0){
    const int cpw = rows/32;
    for(int i=0;i<cpw;i++){
      int chunk = wid*cpw + i;
      int Lb = chunk*1024;
      int L  = Lb + lane*16;
      int row = L >> 7, cb = L & 127;
      int scb = cb ^ ((row&7)<<4);
      gload16(&src[(long)(base_row+row)*K + k0 + (scb>>1)], lds + (Lb>>1));
    }
  };
  auto compute = [&](const u16* As_, const u16* Bs_){
    for(int kc=0;kc<2;kc++){
      const int co = (kc*32 + g*8) ^ ((lr&7)<<3);
      bf16x8 af[MF], bfr[NF];
      for(int m=0;m<MF;m++) af[m]  = *(const bf16x8*)&As_[(wr*WM+m*16+lr)*64 + co];
      for(int n=0;n<NF;n++) bfr[n] = *(const bf16x8*)&Bs_[(wc*WN+n*16+lr)*64 + co];
      for(int m=0;m<MF;m++)
        for(int n=0;n<NF;n++)
          acc[m][n] = __builtin_amdgcn_mfma_f32_16x16x32_bf16(af[m], bfr[n], acc[m][n], 0,0,0);
    }
  };

  const int nk = K/64;
  if constexpr (DBUF){
    stage(A, m0, As[0], BM, 0);
    stage(Bt, n0, Bs[0], BN, 0);
    __syncthreads();
    int cur = 0;
    for(int t=0;t<nk;t++){
      if(t+1<nk){
        stage(A, m0, As[cur^1], BM, (t+1)*64);
        stage(Bt, n0, Bs[cur^1], BN, (t+1)*64);
      }
      compute(As[cur], Bs[cur]);
      __syncthreads();
      cur ^= 1;
    }
  } else {
    for(int t=0;t<nk;t++){
      stage(A, m0, As[0], BM, t*64);
      stage(Bt, n0, Bs[0], BN, t*64);
      __syncthreads();                     // vmcnt(0) drain + barrier
      compute(As[0], Bs[0]);
      __syncthreads();
    }
  }
  for(int m=0;m<MF;m++){
    int row = m0 + wr*WM + m*16 + g*4;
    for(int n=0;n<NF;n++){
      int col = n0 + wc*WN + n*16 + lr;
      float bv = 0.f;
      if constexpr (EPI>=1) bv = bias[col];
      for(int j=0;j<4;j++){
        float v = acc[m][n][j] + bv;
        if constexpr (EPI==2) v = (v >= 0.f) ? v : 0.01f*v;
        C[(long)(row+j)*N + col] = f2b(v);
      }
    }
  }
}

// ------------- flash attention PARTIAL: (Q-tile 64) x (KV-chunk 512) -----
// Round-6 proven structure; bf16 raw-O partials; tree pmax.
template<bool CAUSAL>
__global__ __launch_bounds__(256) void attn_part_k(const u16* __restrict__ Q,
                                                   const u16* __restrict__ Km,
                                                   const u16* __restrict__ Vt,
                                                   u16* __restrict__ Op,
                                                   float* __restrict__ Ml){
  constexpr int LDK = 72;
  constexpr int NCH = 16;    // chunks of 512
  constexpr int CTI = 8;     // 64-wide tiles per chunk
  __shared__ u16 Ks[64*LDK];
  __shared__ u16 Vs[64*LDK];
  __shared__ u16 Ps[4*16*LDK];

  const int qb = blockIdx.x, ci = blockIdx.y;
  if(CAUSAL && ci*CTI > qb) return;

  const int tid = threadIdx.x, wid = tid>>6, lane = tid&63;
  const int g = lane>>4, lr = lane&15, r4 = g*4;
  const int qrow = qb*64 + wid*16;

  bf16x8 qf[2];
  for(int kc=0;kc<2;kc++){
    bf16x8 t = *(const bf16x8*)&Q[(long)(qrow + lr)*HD + kc*32 + g*8];
    for(int i=0;i<8;i++) t[i] = (__bf16)((float)t[i] * 0.1803368801f);
    qf[kc] = t;
  }

  f32x4 o[4]; for(int n=0;n<4;n++) o[n] = (f32x4)0.f;
  float mst = -1e30f, lst = 0.f;

  const int tdiag = qb - ci*CTI;
  const int tmax = CAUSAL ? min(CTI, tdiag + 1) : CTI;

  const int sr0 = tid>>3, sc0 = (tid&7)*8;
  short8 rK0, rK1, rV0, rV1;
  {
    const int kv0 = ci*512;
    rK0 = *(const short8*)&Km[(long)(kv0+sr0)*HD + sc0];
    rK1 = *(const short8*)&Km[(long)(kv0+sr0+32)*HD + sc0];
    rV0 = *(const short8*)&Vt[(long)sr0*SEQ + kv0 + sc0];
    rV1 = *(const short8*)&Vt[(long)(sr0+32)*SEQ + kv0 + sc0];
  }

  for(int t=0; t<tmax; ++t){
    const int kv0 = ci*512 + t*64;
    __syncthreads();
    *(short8*)&Ks[sr0*LDK + sc0]      = rK0;
    *(short8*)&Ks[(sr0+32)*LDK + sc0] = rK1;
    *(short8*)&Vs[sr0*LDK + sc0]      = rV0;
    *(short8*)&Vs[(sr0+32)*LDK + sc0] = rV1;
    __syncthreads();
    if(t+1 < tmax){
      const int kn = kv0 + 64;
      rK0 = *(const short8*)&Km[(long)(kn+sr0)*HD + sc0];
      rK1 = *(const short8*)&Km[(long)(kn+sr0+32)*HD + sc0];
      rV0 = *(const short8*)&Vt[(long)sr0*SEQ + kn + sc0];
      rV1 = *(const short8*)&Vt[(long)(sr0+32)*SEQ + kn + sc0];
    }

    f32x4 s[4]; for(int n=0;n<4;n++) s[n] = (f32x4)0.f;
    for(int kc=0;kc<2;kc++){
      for(int n=0;n<4;n++){
        bf16x8 kf = *(const bf16x8*)&Ks[(n*16+lr)*LDK + kc*32 + g*8];
        s[n] = __builtin_amdgcn_mfma_f32_16x16x32_bf16(kf, qf[kc], s[n], 0,0,0);
      }
    }
    if(CAUSAL && t == tdiag){
      int row = qrow + lr;
      for(int n=0;n<4;n++)
        for(int j=0;j<4;j++)
          if(kv0 + n*16 + r4 + j > row) s[n][j] = -1e30f;
    }
    // tree pmax (depth 4, max3-fusable) + 2 cross-g shuffles
    float m01 = fmaxf(fmaxf(s[0][0],s[0][1]), fmaxf(s[0][2],s[0][3]));
    float m11 = fmaxf(fmaxf(s[1][0],s[1][1]), fmaxf(s[1][2],s[1][3]));
    float m21 = fmaxf(fmaxf(s[2][0],s[2][1]), fmaxf(s[2][2],s[2][3]));
    float m31 = fmaxf(fmaxf(s[3][0],s[3][1]), fmaxf(s[3][2],s[3][3]));
    float pmax = fmaxf(fmaxf(m01,m11), fmaxf(m21,m31));
    pmax = fmaxf(pmax, __shfl_xor(pmax,16));
    pmax = fmaxf(pmax, __shfl_xor(pmax,32));
    if(__any(pmax > mst + 8.f)){
      float mn = fmaxf(mst, pmax);
      float fac = exp2f(mst - mn);
      mst = mn; lst *= fac;
      float fj0 = __shfl(fac, r4+0), fj1 = __shfl(fac, r4+1);
      float fj2 = __shfl(fac, r4+2), fj3 = __shfl(fac, r4+3);
      for(int n=0;n<4;n++){
        o[n][0] *= fj0; o[n][1] *= fj1; o[n][2] *= fj2; o[n][3] *= fj3;
      }
    }
    float rs = 0.f;
    for(int n=0;n<4;n++){
      u16 w[4];
      for(int j=0;j<4;j++){
        float p = exp2f(s[n][j] - mst);
        rs += p;
        __bf16 pb = (__bf16)p;
        union { __bf16 b; u16 u; } cv; cv.b = pb;
        w[j] = cv.u;
      }
      *(s16x4*)&Ps[(wid*16 + lr)*LDK + n*16 + r4] = *(s16x4*)w;
    }
    rs += __shfl_xor(rs,16); rs += __shfl_xor(rs,32);
    lst += rs;
    for(int kc=0;kc<2;kc++){
      bf16x8 pf = *(const bf16x8*)&Ps[(wid*16 + lr)*LDK + kc*32 + g*8];
      for(int n=0;n<4;n++){
        bf16x8 vf = *(const bf16x8*)&Vs[(n*16+lr)*LDK + kc*32 + g*8];
        o[n] = __builtin_amdgcn_mfma_f32_16x16x32_bf16(pf, vf, o[n], 0,0,0);
      }
    }
  }
  const long pr = (long)(qb*NCH + ci)*64;
  for(int n=0;n<4;n++)
    for(int j=0;j<4;j++)
      Op[(pr + wid*16 + r4 + j)*64 + n*16 + lr] = f2b(o[n][j]);
  if(lane < 16){
    Ml[(pr + wid*16 + lr)*2]     = mst;
    Ml[(pr + wid*16 + lr)*2 + 1] = lst;
  }
}

// ------------- flash attention REDUCE: merge 16 chunk partials per row ----
template<bool CAUSAL>
__global__ __launch_bounds__(256) void attn_red_k(const u16* __restrict__ Op,
                                                  const float* __restrict__ Ml,
                                                  u16* __restrict__ O){
  int r = blockIdx.x*4 + (threadIdx.x>>6);
  int d = threadIdx.x & 63;
  int qb = r >> 6, rt = r & 63;
  int nch = CAUSAL ? (qb>>3) + 1 : 16;
  long base = (long)qb*16*64 + rt;
  float m = -1e30f;
  for(int i=0;i<nch;i++) m = fmaxf(m, Ml[(base + i*64)*2]);
  float L = 0.f, acc = 0.f;
  for(int i=0;i<nch;i++){
    float mi = Ml[(base + i*64)*2], li = Ml[(base + i*64)*2 + 1];
    float w = exp2f(mi - m);
    L   += li * w;
    acc += w * b2f(Op[(base + i*64)*64 + d]);
  }
  O[(long)r*HD + d] = f2b(acc / L);
}

extern "C" void kernel_launch(void* const* d_in, const int* in_sizes, int n_in,
                              void* d_out, int out_size, void* d_ws, size_t ws_size,
                              hipStream_t stream){
  const float* enc  = (const float*)d_in[0];
  const float* prev = (const float*)d_in[1];
  const float* wq_m = (const float*)d_in[2];
  const float* wk_m = (const float*)d_in[3];
  const float* wv_m = (const float*)d_in[4];
  const float* wq_c = (const float*)d_in[5];
  const float* wk_c = (const float*)d_in[6];
  const float* wv_c = (const float*)d_in[7];
  const float* w_o  = (const float*)d_in[8];
  const float* ln_g = (const float*)d_in[9];
  const float* ln_b = (const float*)d_in[10];
  const float* w1   = (const float*)d_in[11];
  const float* b1   = (const float*)d_in[12];
  const float* w2   = (const float*)d_in[13];
  const float* b2   = (const float*)d_in[14];
  float* out = (float*)d_out;
  u16* ws  = (u16*)d_ws;

  // workspace layout (u16 element offsets) — total ≈ 76 MB (proven fit)
  u16* wq_m_t = ws;
  u16* wk_c_t = wq_m_t + 4*32768;
  u16* wost   = wq_m_t + 6*32768;
  u16* w1_t   = wost   + 32768;
  u16* w2_t   = w1_t   + 1048576;
  u16* enc_b  = w2_t   + 1048576;
  u16* prev_b = enc_b  + 4194304;
  u16* q_m    = prev_b + 4194304;
  u16* k_m    = q_m    + 524288;
  u16* v_m    = k_m    + 524288;
  u16* v_m_t  = v_m    + 524288;
  u16* head_m = v_m_t  + 524288;
  u16* k_c    = head_m + 524288;
  u16* v_c    = k_c    + 524288;
  u16* v_c_t  = v_c    + 524288;
  u16* q_c    = v_c_t  + 524288;
  u16* head_c = q_c    + 524288;
  u16* mmh    = head_c + 524288;
  u16* mh     = mmh    + 4194304;
  u16* xb     = mh     + 4194304;
  float* xf   = (float*)(xb + 4194304);
  u16* hbuf   = enc_b;                       // FFN mid (enc_b dead by then)
  u16* ffn    = mh;                          // mh dead by then
  u16* Op     = mmh;                         // bf16 partials, 16.8 MB (dead region)
  float* Ml   = (float*)(Op + (long)128*16*64*64);

  dim3 b256(256), tb(32,8);

  copycvt_k<<<dim3(2048), b256, 0, stream>>>(enc, out, enc_b, (long)SEQ*DM/8);
  cvt_k<<<dim3(2048), b256, 0, stream>>>(prev, prev_b, (long)SEQ*DM/8);

  wtrans6_k<<<dim3(2,16,6), tb, 0, stream>>>(wq_m, wk_m, wv_m, wq_c, wk_c, wv_c, wq_m_t);
  transpose_k<1><<<dim3(64,16), tb, 0, stream>>>(w1, w1_t, DM, HFF);
  transpose_k<1><<<dim3(16,64), tb, 0, stream>>>(w2, w2_t, HFF, DM);
  wosum_k<<<dim3(128), b256, 0, stream>>>(w_o, wost);

  gemm2<64,64,0,true><<<dim3(SEQ/64,1,3), b256, 0, stream>>>(prev_b, wq_m_t, q_m, nullptr, HD, DM, 32768, 524288);
  gemm2<64,64,0,true><<<dim3(SEQ/64,1,2), b256, 0, stream>>>(enc_b,  wk_c_t, k_c, nullptr, HD, DM, 32768, 524288);
  vtrans2_k<<<dim3(2,256,2), tb, 0, stream>>>(v_m, v_m_t, v_c, v_c_t);

  attn_part_k<true><<<dim3(SEQ/64, 16), b256, 0, stream>>>(q_m, k_m, v_m_t, Op, Ml);
  attn_red_k<true><<<dim3(SEQ/4), b256, 0, stream>>>(Op, Ml, head_m);
  gemm2<64,128,0,false><<<dim3(SEQ/64,4,1), b256, 0, stream>>>(head_m, wost, mmh, nullptr, DM, HD, 0, 0);

  gemm2<64,64,0,false><<<dim3(SEQ/64,1,1), b256, 0, stream>>>(mmh, wq_m_t + 3*32768, q_c, nullptr, HD, DM, 0, 0);
  attn_part_k<false><<<dim3(SEQ/64, 16), b256, 0, stream>>>(q_c, k_c, v_c_t, Op, Ml);
  attn_red_k<false><<<dim3(SEQ/4), b256, 0, stream>>>(Op, Ml, head_c);
  gemm2<64,128,0,false><<<dim3(SEQ/64,4,1), b256, 0, stream>>>(head_c, wost, mh, nullptr, DM, HD, 0, 0);

  add_ln<true><<<dim3(SEQ/4), b256, 0, stream>>>(mh, prev, ln_g, ln_b, xf, xb);

  // FFN: single-buffer m97 structure (FFN1 proven round 9)
  gemm2<128,128,2,false><<<dim3(SEQ/128,HFF/128,1), b256, 0, stream>>>(xb, w1_t, hbuf, b1, HFF, DM, 0, 0);
  gemm2<64,128,1,false><<<dim3(SEQ/64,4,1),         b256, 0, stream>>>(hbuf, w2_t, ffn, b2, DM, HFF, 0, 0);

  add_ln<false><<<dim3(SEQ/4), b256, 0, stream>>>(ffn, xf, ln_g, ln_b, out + (long)SEQ*DM, nullptr);
}

// Round 11
// 221.968 us; speedup vs baseline: 1.0136x; 1.0136x over previous
//
#include <hip/hip_runtime.h>
#include <hip/hip_bf16.h>

typedef unsigned short u16;
typedef __attribute__((ext_vector_type(4))) float f32x4;
typedef __attribute__((ext_vector_type(8))) __bf16 bf16x8;
typedef __attribute__((ext_vector_type(8))) short short8;
typedef __attribute__((ext_vector_type(4))) short s16x4;

constexpr int SEQ = 8192;
constexpr int DM  = 512;
constexpr int HD  = 64;
constexpr int HFF = 2048;

__device__ __forceinline__ float b2f(u16 u){
  union { unsigned int i; float f; } v; v.i = ((unsigned int)u) << 16; return v.f;
}
__device__ __forceinline__ u16 f2b(float f){
  union { float f; unsigned int i; } v; v.f = f;
  unsigned int r = v.i + 0x7FFFu + ((v.i >> 16) & 1u);
  return (u16)(r >> 16);
}

// async global->LDS, 16B per lane; LDS base must be wave-uniform.
__device__ __forceinline__ void gload16(const u16* g, u16* lds){
  __builtin_amdgcn_global_load_lds(
      (const __attribute__((address_space(1))) void*)g,
      (__attribute__((address_space(3))) void*)lds, 16, 0, 0);
}

// --- fused converts: y=0: out0=enc(fp32)+enc_b(bf16); y=1: prev_b(bf16) ---
__global__ __launch_bounds__(256) void cvt2_k(const float* __restrict__ enc,
                                              const float* __restrict__ prev,
                                              float* __restrict__ outf,
                                              u16* __restrict__ enc_b,
                                              u16* __restrict__ prev_b, long n8){
  long i = blockIdx.x * 256L + threadIdx.x;
  if(i >= n8) return;
  const float* in = blockIdx.y ? prev : enc;
  u16* ob = blockIdx.y ? prev_b : enc_b;
  f32x4 a = ((const f32x4*)in)[i*2];
  f32x4 b = ((const f32x4*)in)[i*2+1];
  if(!blockIdx.y){
    ((f32x4*)outf)[i*2]   = a;
    ((f32x4*)outf)[i*2+1] = b;
  }
  u16 ov[8];
  for(int j=0;j<4;j++){ ov[j] = f2b(a[j]); ov[4+j] = f2b(b[j]); }
  ((short8*)ob)[i] = *(short8*)ov;
}

// ------- batched transpose of the six [512,64] projection weights --------
__global__ __launch_bounds__(256) void wtrans6_k(const float* __restrict__ w0,
                                                 const float* __restrict__ w1,
                                                 const float* __restrict__ w2,
                                                 const float* __restrict__ w3,
                                                 const float* __restrict__ w4,
                                                 const float* __restrict__ w5,
                                                 u16* __restrict__ out){
  __shared__ u16 t[32][33];
  const float* ins[6] = {w0,w1,w2,w3,w4,w5};
  const float* in = ins[blockIdx.z];
  u16* o = out + (long)blockIdx.z * 32768;
  int c0 = blockIdx.x*32, r0 = blockIdx.y*32;
  int tx = threadIdx.x, ty = threadIdx.y;     // blockDim (32,8)
  for(int i=0;i<4;i++)
    t[ty+i*8][tx] = f2b(in[(long)(r0+ty+i*8)*HD + c0+tx]);
  __syncthreads();
  for(int i=0;i<4;i++) o[(long)(c0+ty+i*8)*DM + r0+tx] = t[tx][ty+i*8];
}

// ---------------- generic 32x32 transpose; IN_F: 1=fp32 in, 0=bf16 in ----
template<int IN_F>
__global__ __launch_bounds__(256) void transpose_k(const void* __restrict__ inp,
                                                   u16* __restrict__ out, int R, int C){
  __shared__ u16 t[32][33];
  int c0 = blockIdx.x*32, r0 = blockIdx.y*32;
  int tx = threadIdx.x, ty = threadIdx.y;     // blockDim (32,8)
  for(int i=0;i<4;i++){
    long idx = (long)(r0+ty+i*8)*C + c0+tx;
    u16 v;
    if constexpr (IN_F) v = f2b(((const float*)inp)[idx]);
    else                v = ((const u16*)inp)[idx];
    t[ty+i*8][tx] = v;
  }
  __syncthreads();
  for(int i=0;i<4;i++) out[(long)(c0+ty+i*8)*R + r0+tx] = t[tx][ty+i*8];
}

// ------- batched transpose of two [8192,64] V matrices -> [64,8192] ------
__global__ __launch_bounds__(256) void vtrans2_k(const u16* __restrict__ v0,
                                                 u16* __restrict__ o0,
                                                 const u16* __restrict__ v1,
                                                 u16* __restrict__ o1){
  __shared__ u16 t[32][33];
  const u16* in = blockIdx.z ? v1 : v0;
  u16* o = blockIdx.z ? o1 : o0;
  int c0 = blockIdx.x*32, r0 = blockIdx.y*32;
  int tx = threadIdx.x, ty = threadIdx.y;
  for(int i=0;i<4;i++) t[ty+i*8][tx] = in[(long)(r0+ty+i*8)*HD + c0+tx];
  __syncthreads();
  for(int i=0;i<4;i++) o[(long)(c0+ty+i*8)*SEQ + r0+tx] = t[tx][ty+i*8];
}

// ---------------- w_o head-sum, transposed ----------------
__global__ __launch_bounds__(256) void wosum_k(const float* __restrict__ wo,
                                               u16* __restrict__ outT){
  int tid = blockIdx.x*256 + threadIdx.x;     // 32768 total
  int n = tid >> 6, p = tid & 63;
  float s = 0.f;
  for(int h=0; h<8; h++) s += wo[(long)(h*64+p)*DM + n];
  outT[n*64+p] = f2b(s);
}

// ---------------- fused residual-add + LayerNorm ----------------
template<bool WRITE_BF>
__global__ __launch_bounds__(256) void add_ln(const u16* __restrict__ Xa,
                                              const float* __restrict__ Xb,
                                              const float* __restrict__ G,
                                              const float* __restrict__ Bb,
                                              float* __restrict__ OutF,
                                              u16* __restrict__ OutB){
  int row  = blockIdx.x*4 + (threadIdx.x>>6);
  int lane = threadIdx.x & 63;
  short8 a8 = *(const short8*)&Xa[(long)row*DM + lane*8];
  f32x4 b0 = *(const f32x4*)&Xb[(long)row*DM + lane*8];
  f32x4 b1 = *(const f32x4*)&Xb[(long)row*DM + lane*8 + 4];
  float x[8]; float s=0.f, s2=0.f;
  for(int i=0;i<8;i++){
    float bv = (i<4) ? b0[i] : b1[i-4];
    x[i] = b2f((u16)a8[i]) + bv;
    s += x[i]; s2 += x[i]*x[i];
  }
  for(int o=1;o<64;o<<=1){ s += __shfl_xor(s,o); s2 += __shfl_xor(s2,o); }
  float mu  = s * (1.f/DM);
  float var = s2 * (1.f/DM) - mu*mu;
  float rstd = rsqrtf(var + 1e-5f);
  f32x4 g0 = *(const f32x4*)&G[lane*8];
  f32x4 g1 = *(const f32x4*)&G[lane*8+4];
  f32x4 p0 = *(const f32x4*)&Bb[lane*8];
  f32x4 p1 = *(const f32x4*)&Bb[lane*8+4];
  float of[8]; u16 ob[8];
  for(int i=0;i<8;i++){
    float gv = (i<4)?g0[i]:g1[i-4], bv2 = (i<4)?p0[i]:p1[i-4];
    float v = (x[i]-mu)*rstd*gv + bv2;
    of[i] = v; ob[i] = f2b(v);
  }
  *(f32x4*)&OutF[(long)row*DM + lane*8]     = *(f32x4*)&of[0];
  *(f32x4*)&OutF[(long)row*DM + lane*8 + 4] = *(f32x4*)&of[4];
  if constexpr (WRITE_BF)
    *(short8*)&OutB[(long)row*DM + lane*8] = *(short8*)ob;
}

// ---- GEMM v2: global_load_lds staging, source-swizzled LDS.
// DBUF=true: double-buffered stage-early. DBUF=false: single-buffer (m97).
template<int BM,int BN,int EPI,bool DBUF>
__global__ __launch_bounds__(256) void gemm2(const u16* __restrict__ A,
                                             const u16* __restrict__ Bt,
                                             u16* __restrict__ C,
                                             const float* __restrict__ bias,
                                             int N, int K, long sB, long sC){
  constexpr int WR=2, WC=2;
  constexpr int WM = BM/WR, WN = BN/WC;
  constexpr int MF = WM/16, NF = WN/16;
  constexpr int NB = DBUF ? 2 : 1;
  __shared__ u16 As[NB][BM*64];
  __shared__ u16 Bs[NB][BN*64];

  const int tid = threadIdx.x;
  const int wid = tid >> 6, lane = tid & 63;
  const int g = lane >> 4, lr = lane & 15;
  const int m0 = blockIdx.x * BM;
  const int n0 = blockIdx.y * BN;
  Bt += (long)blockIdx.z * sB;
  C  += (long)blockIdx.z * sC;
  const int wr = wid / WC, wc = wid % WC;

  f32x4 acc[MF][NF];
  for(int m=0;m<MF;m++) for(int n=0;n<NF;n++) acc[m][n] = (f32x4)0.f;

  auto stage = [&](const u16* src, int base_row, u16* lds, int rows, int k0){
    const int cpw = rows/32;
    for(int i=0;i<cpw;i++){
      int chunk = wid*cpw + i;
      int Lb = chunk*1024;
      int L  = Lb + lane*16;
      int row = L >> 7, cb = L & 127;
      int scb = cb ^ ((row&7)<<4);
      gload16(&src[(long)(base_row+row)*K + k0 + (scb>>1)], lds + (Lb>>1));
    }
  };
  auto compute = [&](const u16* As_, const u16* Bs_){
    for(int kc=0;kc<2;kc++){
      const int co = (kc*32 + g*8) ^ ((lr&7)<<3);
      bf16x8 af[MF], bfr[NF];
      for(int m=0;m<MF;m++) af[m]  = *(const bf16x8*)&As_[(wr*WM+m*16+lr)*64 + co];
      for(int n=0;n<NF;n++) bfr[n] = *(const bf16x8*)&Bs_[(wc*WN+n*16+lr)*64 + co];
      for(int m=0;m<MF;m++)
        for(int n=0;n<NF;n++)
          acc[m][n] = __builtin_amdgcn_mfma_f32_16x16x32_bf16(af[m], bfr[n], acc[m][n], 0,0,0);
    }
  };

  const int nk = K/64;
  if constexpr (DBUF){
    stage(A, m0, As[0], BM, 0);
    stage(Bt, n0, Bs[0], BN, 0);
    __syncthreads();
    int cur = 0;
    for(int t=0;t<nk;t++){
      if(t+1<nk){
        stage(A, m0, As[cur^1], BM, (t+1)*64);
        stage(Bt, n0, Bs[cur^1], BN, (t+1)*64);
      }
      compute(As[cur], Bs[cur]);
      __syncthreads();
      cur ^= 1;
    }
  } else {
    for(int t=0;t<nk;t++){
      stage(A, m0, As[0], BM, t*64);
      stage(Bt, n0, Bs[0], BN, t*64);
      __syncthreads();                     // vmcnt(0) drain + barrier
      compute(As[0], Bs[0]);
      __syncthreads();
    }
  }
  for(int m=0;m<MF;m++){
    int row = m0 + wr*WM + m*16 + g*4;
    for(int n=0;n<NF;n++){
      int col = n0 + wc*WN + n*16 + lr;
      float bv = 0.f;
      if constexpr (EPI>=1) bv = bias[col];
      for(int j=0;j<4;j++){
        float v = acc[m][n][j] + bv;
        if constexpr (EPI==2) v = (v >= 0.f) ? v : 0.01f*v;
        C[(long)(row+j)*N + col] = f2b(v);
      }
    }
  }
}

// ------------- flash attention PARTIAL: (Q-tile 64) x (KV-chunk 512) -----
// Round-6 structure; LDS packed via XOR-swizzle (24.5KB -> 6 blocks/CU);
// setprio(1) around MFMA clusters; bf16 raw-O partials; tree pmax.
template<bool CAUSAL>
__global__ __launch_bounds__(256) void attn_part_k(const u16* __restrict__ Q,
                                                   const u16* __restrict__ Km,
                                                   const u16* __restrict__ Vt,
                                                   u16* __restrict__ Op,
                                                   float* __restrict__ Ml){
  constexpr int NCH = 16;    // chunks of 512
  constexpr int CTI = 8;     // 64-wide tiles per chunk
  __shared__ u16 Ks[64*64];       // swizzled content: col ^= ((row&7)<<3)
  __shared__ u16 Vs[64*64];
  __shared__ u16 Ps[4*16*64];

  const int qb = blockIdx.x, ci = blockIdx.y;
  if(CAUSAL && ci*CTI > qb) return;

  const int tid = threadIdx.x, wid = tid>>6, lane = tid&63;
  const int g = lane>>4, lr = lane&15, r4 = g*4;
  const int qrow = qb*64 + wid*16;
  const int rsw = (lr&7)<<3;                 // read-side XOR (u16 units)

  bf16x8 qf[2];
  for(int kc=0;kc<2;kc++){
    bf16x8 t = *(const bf16x8*)&Q[(long)(qrow + lr)*HD + kc*32 + g*8];
    for(int i=0;i<8;i++) t[i] = (__bf16)((float)t[i] * 0.1803368801f);
    qf[kc] = t;
  }

  f32x4 o[4]; for(int n=0;n<4;n++) o[n] = (f32x4)0.f;
  float mst = -1e30f, lst = 0.f;

  const int tdiag = qb - ci*CTI;
  const int tmax = CAUSAL ? min(CTI, tdiag + 1) : CTI;

  const int sr0 = tid>>3, sc0 = (tid&7)*8;
  const int wsw = (sr0&7)<<3;                // write-side XOR ((sr0+32)&7 == sr0&7)
  short8 rK0, rK1, rV0, rV1;
  {
    const int kv0 = ci*512;
    rK0 = *(const short8*)&Km[(long)(kv0+sr0)*HD + sc0];
    rK1 = *(const short8*)&Km[(long)(kv0+sr0+32)*HD + sc0];
    rV0 = *(const short8*)&Vt[(long)sr0*SEQ + kv0 + sc0];
    rV1 = *(const short8*)&Vt[(long)(sr0+32)*SEQ + kv0 + sc0];
  }

  for(int t=0; t<tmax; ++t){
    const int kv0 = ci*512 + t*64;
    __syncthreads();
    *(short8*)&Ks[sr0*64      + (sc0 ^ wsw)] = rK0;
    *(short8*)&Ks[(sr0+32)*64 + (sc0 ^ wsw)] = rK1;
    *(short8*)&Vs[sr0*64      + (sc0 ^ wsw)] = rV0;
    *(short8*)&Vs[(sr0+32)*64 + (sc0 ^ wsw)] = rV1;
    __syncthreads();
    if(t+1 < tmax){
      const int kn = kv0 + 64;
      rK0 = *(const short8*)&Km[(long)(kn+sr0)*HD + sc0];
      rK1 = *(const short8*)&Km[(long)(kn+sr0+32)*HD + sc0];
      rV0 = *(const short8*)&Vt[(long)sr0*SEQ + kn + sc0];
      rV1 = *(const short8*)&Vt[(long)(sr0+32)*SEQ + kn + sc0];
    }

    f32x4 s[4]; for(int n=0;n<4;n++) s[n] = (f32x4)0.f;
    __builtin_amdgcn_s_setprio(1);
    for(int kc=0;kc<2;kc++){
      const int co = (kc*32 + g*8) ^ rsw;
      for(int n=0;n<4;n++){
        bf16x8 kf = *(const bf16x8*)&Ks[(n*16+lr)*64 + co];
        s[n] = __builtin_amdgcn_mfma_f32_16x16x32_bf16(kf, qf[kc], s[n], 0,0,0);
      }
    }
    __builtin_amdgcn_s_setprio(0);
    if(CAUSAL && t == tdiag){
      int row = qrow + lr;
      for(int n=0;n<4;n++)
        for(int j=0;j<4;j++)
          if(kv0 + n*16 + r4 + j > row) s[n][j] = -1e30f;
    }
    // tree pmax (depth 4) + 2 cross-g shuffles
    float m01 = fmaxf(fmaxf(s[0][0],s[0][1]), fmaxf(s[0][2],s[0][3]));
    float m11 = fmaxf(fmaxf(s[1][0],s[1][1]), fmaxf(s[1][2],s[1][3]));
    float m21 = fmaxf(fmaxf(s[2][0],s[2][1]), fmaxf(s[2][2],s[2][3]));
    float m31 = fmaxf(fmaxf(s[3][0],s[3][1]), fmaxf(s[3][2],s[3][3]));
    float pmax = fmaxf(fmaxf(m01,m11), fmaxf(m21,m31));
    pmax = fmaxf(pmax, __shfl_xor(pmax,16));
    pmax = fmaxf(pmax, __shfl_xor(pmax,32));
    if(__any(pmax > mst + 8.f)){
      float mn = fmaxf(mst, pmax);
      float fac = exp2f(mst - mn);
      mst = mn; lst *= fac;
      float fj0 = __shfl(fac, r4+0), fj1 = __shfl(fac, r4+1);
      float fj2 = __shfl(fac, r4+2), fj3 = __shfl(fac, r4+3);
      for(int n=0;n<4;n++){
        o[n][0] *= fj0; o[n][1] *= fj1; o[n][2] *= fj2; o[n][3] *= fj3;
      }
    }
    float rs = 0.f;
    for(int n=0;n<4;n++){
      u16 w[4];
      for(int j=0;j<4;j++){
        float p = exp2f(s[n][j] - mst);
        rs += p;
        __bf16 pb = (__bf16)p;
        union { __bf16 b; u16 u; } cv; cv.b = pb;
        w[j] = cv.u;
      }
      // store at swizzled col; base (n*16+r4) mult of 4, XOR bits >=3: contiguity ok
      *(s16x4*)&Ps[(wid*16 + lr)*64 + ((n*16 + r4) ^ rsw)] = *(s16x4*)w;
    }
    rs += __shfl_xor(rs,16); rs += __shfl_xor(rs,32);
    lst += rs;
    __builtin_amdgcn_s_setprio(1);
    for(int kc=0;kc<2;kc++){
      const int co = (kc*32 + g*8) ^ rsw;
      bf16x8 pf = *(const bf16x8*)&Ps[(wid*16 + lr)*64 + co];
      for(int n=0;n<4;n++){
        bf16x8 vf = *(const bf16x8*)&Vs[(n*16+lr)*64 + co];
        o[n] = __builtin_amdgcn_mfma_f32_16x16x32_bf16(pf, vf, o[n], 0,0,0);
      }
    }
    __builtin_amdgcn_s_setprio(0);
  }
  const long pr = (long)(qb*NCH + ci)*64;
  for(int n=0;n<4;n++)
    for(int j=0;j<4;j++)
      Op[(pr + wid*16 + r4 + j)*64 + n*16 + lr] = f2b(o[n][j]);
  if(lane < 16){
    Ml[(pr + wid*16 + lr)*2]     = mst;
    Ml[(pr + wid*16 + lr)*2 + 1] = lst;
  }
}

// ------------- flash attention REDUCE: merge 16 chunk partials per row ----
template<bool CAUSAL>
__global__ __launch_bounds__(256) void attn_red_k(const u16* __restrict__ Op,
                                                  const float* __restrict__ Ml,
                                                  u16* __restrict__ O){
  int r = blockIdx.x*4 + (threadIdx.x>>6);
  int d = threadIdx.x & 63;
  int qb = r >> 6, rt = r & 63;
  int nch = CAUSAL ? (qb>>3) + 1 : 16;
  long base = (long)qb*16*64 + rt;
  float m = -1e30f;
  for(int i=0;i<nch;i++) m = fmaxf(m, Ml[(base + i*64)*2]);
  float L = 0.f, acc = 0.f;
  for(int i=0;i<nch;i++){
    float mi = Ml[(base + i*64)*2], li = Ml[(base + i*64)*2 + 1];
    float w = exp2f(mi - m);
    L   += li * w;
    acc += w * b2f(Op[(base + i*64)*64 + d]);
  }
  O[(long)r*HD + d] = f2b(acc / L);
}

extern "C" void kernel_launch(void* const* d_in, const int* in_sizes, int n_in,
                              void* d_out, int out_size, void* d_ws, size_t ws_size,
                              hipStream_t stream){
  const float* enc  = (const float*)d_in[0];
  const float* prev = (const float*)d_in[1];
  const float* wq_m = (const float*)d_in[2];
  const float* wk_m = (const float*)d_in[3];
  const float* wv_m = (const float*)d_in[4];
  const float* wq_c = (const float*)d_in[5];
  const float* wk_c = (const float*)d_in[6];
  const float* wv_c = (const float*)d_in[7];
  const float* w_o  = (const float*)d_in[8];
  const float* ln_g = (const float*)d_in[9];
  const float* ln_b = (const float*)d_in[10];
  const float* w1   = (const float*)d_in[11];
  const float* b1   = (const float*)d_in[12];
  const float* w2   = (const float*)d_in[13];
  const float* b2   = (const float*)d_in[14];
  float* out = (float*)d_out;
  u16* ws  = (u16*)d_ws;

  // workspace layout (u16 element offsets) — total ≈ 76 MB (proven fit)
  u16* wq_m_t = ws;
  u16* wk_c_t = wq_m_t + 4*32768;
  u16* wost   = wq_m_t + 6*32768;
  u16* w1_t   = wost   + 32768;
  u16* w2_t   = w1_t   + 1048576;
  u16* enc_b  = w2_t   + 1048576;
  u16* prev_b = enc_b  + 4194304;
  u16* q_m    = prev_b + 4194304;
  u16* k_m    = q_m    + 524288;
  u16* v_m    = k_m    + 524288;
  u16* v_m_t  = v_m    + 524288;
  u16* head_m = v_m_t  + 524288;
  u16* k_c    = head_m + 524288;
  u16* v_c    = k_c    + 524288;
  u16* v_c_t  = v_c    + 524288;
  u16* q_c    = v_c_t  + 524288;
  u16* head_c = q_c    + 524288;
  u16* mmh    = head_c + 524288;
  u16* mh     = mmh    + 4194304;
  u16* xb     = mh     + 4194304;
  float* xf   = (float*)(xb + 4194304);
  u16* hbuf   = enc_b;                       // FFN mid (enc_b dead by then)
  u16* ffn    = mh;                          // mh dead by then
  u16* Op     = mmh;                         // bf16 partials (dead region)
  float* Ml   = (float*)(Op + (long)128*16*64*64);

  dim3 b256(256), tb(32,8);

  cvt2_k<<<dim3(2048,2), b256, 0, stream>>>(enc, prev, out, enc_b, prev_b, (long)SEQ*DM/8);

  wtrans6_k<<<dim3(2,16,6), tb, 0, stream>>>(wq_m, wk_m, wv_m, wq_c, wk_c, wv_c, wq_m_t);
  transpose_k<1><<<dim3(64,16), tb, 0, stream>>>(w1, w1_t, DM, HFF);
  transpose_k<1><<<dim3(16,64), tb, 0, stream>>>(w2, w2_t, HFF, DM);
  wosum_k<<<dim3(128), b256, 0, stream>>>(w_o, wost);

  gemm2<64,64,0,true><<<dim3(SEQ/64,1,3), b256, 0, stream>>>(prev_b, wq_m_t, q_m, nullptr, HD, DM, 32768, 524288);
  gemm2<64,64,0,true><<<dim3(SEQ/64,1,2), b256, 0, stream>>>(enc_b,  wk_c_t, k_c, nullptr, HD, DM, 32768, 524288);
  vtrans2_k<<<dim3(2,256,2), tb, 0, stream>>>(v_m, v_m_t, v_c, v_c_t);

  attn_part_k<true><<<dim3(SEQ/64, 16), b256, 0, stream>>>(q_m, k_m, v_m_t, Op, Ml);
  attn_red_k<true><<<dim3(SEQ/4), b256, 0, stream>>>(Op, Ml, head_m);
  gemm2<64,128,0,false><<<dim3(SEQ/64,4,1), b256, 0, stream>>>(head_m, wost, mmh, nullptr, DM, HD, 0, 0);

  gemm2<64,64,0,false><<<dim3(SEQ/64,1,1), b256, 0, stream>>>(mmh, wq_m_t + 3*32768, q_c, nullptr, HD, DM, 0, 0);
  attn_part_k<false><<<dim3(SEQ/64, 16), b256, 0, stream>>>(q_c, k_c, v_c_t, Op, Ml);
  attn_red_k<false><<<dim3(SEQ/4), b256, 0, stream>>>(Op, Ml, head_c);
  gemm2<64,128,0,false><<<dim3(SEQ/64,4,1), b256, 0, stream>>>(head_c, wost, mh, nullptr, DM, HD, 0, 0);

  add_ln<true><<<dim3(SEQ/4), b256, 0, stream>>>(mh, prev, ln_g, ln_b, xf, xb);

  // FFN: single-buffer m97 structure
  gemm2<128,128,2,false><<<dim3(SEQ/128,HFF/128,1), b256, 0, stream>>>(xb, w1_t, hbuf, b1, HFF, DM, 0, 0);
  gemm2<64,128,1,false><<<dim3(SEQ/64,4,1),         b256, 0, stream>>>(hbuf, w2_t, ffn, b2, DM, HFF, 0, 0);

  add_ln<false><<<dim3(SEQ/4), b256, 0, stream>>>(ffn, xf, ln_g, ln_b, out + (long)SEQ*DM, nullptr);
}

// Round 12
// 219.764 us; speedup vs baseline: 1.0237x; 1.0100x over previous
//
#include <hip/hip_runtime.h>
#include <hip/hip_bf16.h>

typedef unsigned short u16;
typedef __attribute__((ext_vector_type(4))) float f32x4;
typedef __attribute__((ext_vector_type(8))) __bf16 bf16x8;
typedef __attribute__((ext_vector_type(8))) short short8;
typedef __attribute__((ext_vector_type(4))) short s16x4;

constexpr int SEQ = 8192;
constexpr int DM  = 512;
constexpr int HD  = 64;
constexpr int HFF = 2048;

__device__ __forceinline__ float b2f(u16 u){
  union { unsigned int i; float f; } v; v.i = ((unsigned int)u) << 16; return v.f;
}
__device__ __forceinline__ u16 f2b(float f){
  union { float f; unsigned int i; } v; v.f = f;
  unsigned int r = v.i + 0x7FFFu + ((v.i >> 16) & 1u);
  return (u16)(r >> 16);
}

// async global->LDS, 16B per lane; LDS base must be wave-uniform.
__device__ __forceinline__ void gload16(const u16* g, u16* lds){
  __builtin_amdgcn_global_load_lds(
      (const __attribute__((address_space(1))) void*)g,
      (__attribute__((address_space(3))) void*)lds, 16, 0, 0);
}

// --- fused converts: y=0: out0=enc(fp32)+enc_b(bf16); y=1: prev_b(bf16) ---
__global__ __launch_bounds__(256) void cvt2_k(const float* __restrict__ enc,
                                              const float* __restrict__ prev,
                                              float* __restrict__ outf,
                                              u16* __restrict__ enc_b,
                                              u16* __restrict__ prev_b, long n8){
  long i = blockIdx.x * 256L + threadIdx.x;
  if(i >= n8) return;
  const float* in = blockIdx.y ? prev : enc;
  u16* ob = blockIdx.y ? prev_b : enc_b;
  f32x4 a = ((const f32x4*)in)[i*2];
  f32x4 b = ((const f32x4*)in)[i*2+1];
  if(!blockIdx.y){
    ((f32x4*)outf)[i*2]   = a;
    ((f32x4*)outf)[i*2+1] = b;
  }
  u16 ov[8];
  for(int j=0;j<4;j++){ ov[j] = f2b(a[j]); ov[4+j] = f2b(b[j]); }
  ((short8*)ob)[i] = *(short8*)ov;
}

// --- fused weight prep: z=0..5 proj transposes, z=6 w1^T, z=7 w2^T, z=8 wosum
__global__ __launch_bounds__(256) void prep_k(const float* __restrict__ p0,
                                              const float* __restrict__ p1,
                                              const float* __restrict__ p2,
                                              const float* __restrict__ p3,
                                              const float* __restrict__ p4,
                                              const float* __restrict__ p5,
                                              const float* __restrict__ w1,
                                              const float* __restrict__ w2,
                                              const float* __restrict__ wo,
                                              u16* __restrict__ out6,
                                              u16* __restrict__ w1_t,
                                              u16* __restrict__ w2_t,
                                              u16* __restrict__ wost){
  __shared__ u16 t[32][33];
  const int z = blockIdx.z;
  const int tx = threadIdx.x, ty = threadIdx.y;   // block (32,8)
  if(z < 6){                                      // [512,64] -> [64,512]
    if(blockIdx.x >= 2) return;
    const float* ins[6] = {p0,p1,p2,p3,p4,p5};
    const float* in = ins[z];
    u16* o = out6 + (long)z * 32768;
    int c0 = blockIdx.x*32, r0 = blockIdx.y*32;
    for(int i=0;i<4;i++)
      t[ty+i*8][tx] = f2b(in[(long)(r0+ty+i*8)*HD + c0+tx]);
    __syncthreads();
    for(int i=0;i<4;i++) o[(long)(c0+ty+i*8)*DM + r0+tx] = t[tx][ty+i*8];
  } else if(z == 6){                              // w1 [512,2048] -> [2048,512]
    int c0 = blockIdx.x*32, r0 = blockIdx.y*32;   // grid (64,16) exact
    for(int i=0;i<4;i++)
      t[ty+i*8][tx] = f2b(w1[(long)(r0+ty+i*8)*HFF + c0+tx]);
    __syncthreads();
    for(int i=0;i<4;i++) w1_t[(long)(c0+ty+i*8)*DM + r0+tx] = t[tx][ty+i*8];
  } else if(z == 7){                              // w2 [2048,512] -> [512,2048]
    int c0 = blockIdx.y*32, r0 = blockIdx.x*32;   // swapped roles
    for(int i=0;i<4;i++)
      t[ty+i*8][tx] = f2b(w2[(long)(r0+ty+i*8)*DM + c0+tx]);
    __syncthreads();
    for(int i=0;i<4;i++) w2_t[(long)(c0+ty+i*8)*HFF + r0+tx] = t[tx][ty+i*8];
  } else {                                        // wosum: 128 x 256 threads
    int fb = blockIdx.y*64 + blockIdx.x;
    if(fb >= 128) return;
    int tid = fb*256 + ty*32 + tx;
    int n = tid >> 6, p = tid & 63;
    float s = 0.f;
    for(int h=0; h<8; h++) s += wo[(long)(h*64+p)*DM + n];
    wost[n*64+p] = f2b(s);
  }
}

// ------- batched transpose of two [8192,64] V matrices -> [64,8192] ------
__global__ __launch_bounds__(256) void vtrans2_k(const u16* __restrict__ v0,
                                                 u16* __restrict__ o0,
                                                 const u16* __restrict__ v1,
                                                 u16* __restrict__ o1){
  __shared__ u16 t[32][33];
  const u16* in = blockIdx.z ? v1 : v0;
  u16* o = blockIdx.z ? o1 : o0;
  int c0 = blockIdx.x*32, r0 = blockIdx.y*32;
  int tx = threadIdx.x, ty = threadIdx.y;
  for(int i=0;i<4;i++) t[ty+i*8][tx] = in[(long)(r0+ty+i*8)*HD + c0+tx];
  __syncthreads();
  for(int i=0;i<4;i++) o[(long)(c0+ty+i*8)*SEQ + r0+tx] = t[tx][ty+i*8];
}

// ---------------- fused residual-add + LayerNorm ----------------
template<bool WRITE_BF>
__global__ __launch_bounds__(256) void add_ln(const u16* __restrict__ Xa,
                                              const float* __restrict__ Xb,
                                              const float* __restrict__ G,
                                              const float* __restrict__ Bb,
                                              float* __restrict__ OutF,
                                              u16* __restrict__ OutB){
  int row  = blockIdx.x*4 + (threadIdx.x>>6);
  int lane = threadIdx.x & 63;
  short8 a8 = *(const short8*)&Xa[(long)row*DM + lane*8];
  f32x4 b0 = *(const f32x4*)&Xb[(long)row*DM + lane*8];
  f32x4 b1 = *(const f32x4*)&Xb[(long)row*DM + lane*8 + 4];
  float x[8]; float s=0.f, s2=0.f;
  for(int i=0;i<8;i++){
    float bv = (i<4) ? b0[i] : b1[i-4];
    x[i] = b2f((u16)a8[i]) + bv;
    s += x[i]; s2 += x[i]*x[i];
  }
  for(int o=1;o<64;o<<=1){ s += __shfl_xor(s,o); s2 += __shfl_xor(s2,o); }
  float mu  = s * (1.f/DM);
  float var = s2 * (1.f/DM) - mu*mu;
  float rstd = rsqrtf(var + 1e-5f);
  f32x4 g0 = *(const f32x4*)&G[lane*8];
  f32x4 g1 = *(const f32x4*)&G[lane*8+4];
  f32x4 p0 = *(const f32x4*)&Bb[lane*8];
  f32x4 p1 = *(const f32x4*)&Bb[lane*8+4];
  float of[8]; u16 ob[8];
  for(int i=0;i<8;i++){
    float gv = (i<4)?g0[i]:g1[i-4], bv2 = (i<4)?p0[i]:p1[i-4];
    float v = (x[i]-mu)*rstd*gv + bv2;
    of[i] = v; ob[i] = f2b(v);
  }
  *(f32x4*)&OutF[(long)row*DM + lane*8]     = *(f32x4*)&of[0];
  *(f32x4*)&OutF[(long)row*DM + lane*8 + 4] = *(f32x4*)&of[4];
  if constexpr (WRITE_BF)
    *(short8*)&OutB[(long)row*DM + lane*8] = *(short8*)ob;
}

// ---- GEMM v2: global_load_lds staging, source-swizzled LDS.
template<int BM,int BN,int EPI,bool DBUF>
__global__ __launch_bounds__(256) void gemm2(const u16* __restrict__ A,
                                             const u16* __restrict__ Bt,
                                             u16* __restrict__ C,
                                             const float* __restrict__ bias,
                                             int N, int K, long sB, long sC){
  constexpr int WR=2, WC=2;
  constexpr int WM = BM/WR, WN = BN/WC;
  constexpr int MF = WM/16, NF = WN/16;
  constexpr int NB = DBUF ? 2 : 1;
  __shared__ u16 As[NB][BM*64];
  __shared__ u16 Bs[NB][BN*64];

  const int tid = threadIdx.x;
  const int wid = tid >> 6, lane = tid & 63;
  const int g = lane >> 4, lr = lane & 15;
  const int m0 = blockIdx.x * BM;
  const int n0 = blockIdx.y * BN;
  Bt += (long)blockIdx.z * sB;
  C  += (long)blockIdx.z * sC;
  const int wr = wid / WC, wc = wid % WC;

  f32x4 acc[MF][NF];
  for(int m=0;m<MF;m++) for(int n=0;n<NF;n++) acc[m][n] = (f32x4)0.f;

  auto stage = [&](const u16* src, int base_row, u16* lds, int rows, int k0){
    const int cpw = rows/32;
    for(int i=0;i<cpw;i++){
      int chunk = wid*cpw + i;
      int Lb = chunk*1024;
      int L  = Lb + lane*16;
      int row = L >> 7, cb = L & 127;
      int scb = cb ^ ((row&7)<<4);
      gload16(&src[(long)(base_row+row)*K + k0 + (scb>>1)], lds + (Lb>>1));
    }
  };
  auto compute = [&](const u16* As_, const u16* Bs_){
    for(int kc=0;kc<2;kc++){
      const int co = (kc*32 + g*8) ^ ((lr&7)<<3);
      bf16x8 af[MF], bfr[NF];
      for(int m=0;m<MF;m++) af[m]  = *(const bf16x8*)&As_[(wr*WM+m*16+lr)*64 + co];
      for(int n=0;n<NF;n++) bfr[n] = *(const bf16x8*)&Bs_[(wc*WN+n*16+lr)*64 + co];
      for(int m=0;m<MF;m++)
        for(int n=0;n<NF;n++)
          acc[m][n] = __builtin_amdgcn_mfma_f32_16x16x32_bf16(af[m], bfr[n], acc[m][n], 0,0,0);
    }
  };

  const int nk = K/64;
  if constexpr (DBUF){
    stage(A, m0, As[0], BM, 0);
    stage(Bt, n0, Bs[0], BN, 0);
    __syncthreads();
    int cur = 0;
    for(int t=0;t<nk;t++){
      if(t+1<nk){
        stage(A, m0, As[cur^1], BM, (t+1)*64);
        stage(Bt, n0, Bs[cur^1], BN, (t+1)*64);
      }
      compute(As[cur], Bs[cur]);
      __syncthreads();
      cur ^= 1;
    }
  } else {
    for(int t=0;t<nk;t++){
      stage(A, m0, As[0], BM, t*64);
      stage(Bt, n0, Bs[0], BN, t*64);
      __syncthreads();                     // vmcnt(0) drain + barrier
      compute(As[0], Bs[0]);
      __syncthreads();
    }
  }
  for(int m=0;m<MF;m++){
    int row = m0 + wr*WM + m*16 + g*4;
    for(int n=0;n<NF;n++){
      int col = n0 + wc*WN + n*16 + lr;
      float bv = 0.f;
      if constexpr (EPI>=1) bv = bias[col];
      for(int j=0;j<4;j++){
        float v = acc[m][n][j] + bv;
        if constexpr (EPI==2) v = (v >= 0.f) ? v : 0.01f*v;
        C[(long)(row+j)*N + col] = f2b(v);
      }
    }
  }
}

// ------------- flash attention PARTIAL: (Q-tile 64) x (KV-chunk 512) -----
// Swizzle-packed LDS (24.5KB); launch_bounds(256,8) pins VGPR<=64 so the
// 64-VGPR wave quantum holds -> 6 blocks/CU (LDS-bound). setprio on MFMA.
template<bool CAUSAL>
__global__ __launch_bounds__(256, 8) void attn_part_k(const u16* __restrict__ Q,
                                                      const u16* __restrict__ Km,
                                                      const u16* __restrict__ Vt,
                                                      u16* __restrict__ Op,
                                                      float* __restrict__ Ml){
  constexpr int NCH = 16;    // chunks of 512
  constexpr int CTI = 8;     // 64-wide tiles per chunk
  __shared__ u16 Ks[64*64];       // swizzled content: col ^= ((row&7)<<3)
  __shared__ u16 Vs[64*64];
  __shared__ u16 Ps[4*16*64];

  const int qb = blockIdx.x, ci = blockIdx.y;
  if(CAUSAL && ci*CTI > qb) return;

  const int tid = threadIdx.x, wid = tid>>6, lane = tid&63;
  const int g = lane>>4, lr = lane&15, r4 = g*4;
  const int qrow = qb*64 + wid*16;
  const int rsw = (lr&7)<<3;                 // read-side XOR (u16 units)

  bf16x8 qf[2];
  for(int kc=0;kc<2;kc++){
    bf16x8 t = *(const bf16x8*)&Q[(long)(qrow + lr)*HD + kc*32 + g*8];
    for(int i=0;i<8;i++) t[i] = (__bf16)((float)t[i] * 0.1803368801f);
    qf[kc] = t;
  }

  f32x4 o[4]; for(int n=0;n<4;n++) o[n] = (f32x4)0.f;
  float mst = -1e30f, lst = 0.f;

  const int tdiag = qb - ci*CTI;
  const int tmax = CAUSAL ? min(CTI, tdiag + 1) : CTI;

  const int sr0 = tid>>3, sc0 = (tid&7)*8;
  const int wsw = (sr0&7)<<3;
  short8 rK0, rK1, rV0, rV1;
  {
    const int kv0 = ci*512;
    rK0 = *(const short8*)&Km[(long)(kv0+sr0)*HD + sc0];
    rK1 = *(const short8*)&Km[(long)(kv0+sr0+32)*HD + sc0];
    rV0 = *(const short8*)&Vt[(long)sr0*SEQ + kv0 + sc0];
    rV1 = *(const short8*)&Vt[(long)(sr0+32)*SEQ + kv0 + sc0];
  }

  for(int t=0; t<tmax; ++t){
    const int kv0 = ci*512 + t*64;
    __syncthreads();
    *(short8*)&Ks[sr0*64      + (sc0 ^ wsw)] = rK0;
    *(short8*)&Ks[(sr0+32)*64 + (sc0 ^ wsw)] = rK1;
    *(short8*)&Vs[sr0*64      + (sc0 ^ wsw)] = rV0;
    *(short8*)&Vs[(sr0+32)*64 + (sc0 ^ wsw)] = rV1;
    __syncthreads();
    if(t+1 < tmax){
      const int kn = kv0 + 64;
      rK0 = *(const short8*)&Km[(long)(kn+sr0)*HD + sc0];
      rK1 = *(const short8*)&Km[(long)(kn+sr0+32)*HD + sc0];
      rV0 = *(const short8*)&Vt[(long)sr0*SEQ + kn + sc0];
      rV1 = *(const short8*)&Vt[(long)(sr0+32)*SEQ + kn + sc0];
    }

    f32x4 s[4]; for(int n=0;n<4;n++) s[n] = (f32x4)0.f;
    __builtin_amdgcn_s_setprio(1);
    for(int kc=0;kc<2;kc++){
      const int co = (kc*32 + g*8) ^ rsw;
      for(int n=0;n<4;n++){
        bf16x8 kf = *(const bf16x8*)&Ks[(n*16+lr)*64 + co];
        s[n] = __builtin_amdgcn_mfma_f32_16x16x32_bf16(kf, qf[kc], s[n], 0,0,0);
      }
    }
    __builtin_amdgcn_s_setprio(0);
    if(CAUSAL && t == tdiag){
      int row = qrow + lr;
      for(int n=0;n<4;n++)
        for(int j=0;j<4;j++)
          if(kv0 + n*16 + r4 + j > row) s[n][j] = -1e30f;
    }
    float m01 = fmaxf(fmaxf(s[0][0],s[0][1]), fmaxf(s[0][2],s[0][3]));
    float m11 = fmaxf(fmaxf(s[1][0],s[1][1]), fmaxf(s[1][2],s[1][3]));
    float m21 = fmaxf(fmaxf(s[2][0],s[2][1]), fmaxf(s[2][2],s[2][3]));
    float m31 = fmaxf(fmaxf(s[3][0],s[3][1]), fmaxf(s[3][2],s[3][3]));
    float pmax = fmaxf(fmaxf(m01,m11), fmaxf(m21,m31));
    pmax = fmaxf(pmax, __shfl_xor(pmax,16));
    pmax = fmaxf(pmax, __shfl_xor(pmax,32));
    if(__any(pmax > mst + 8.f)){
      float mn = fmaxf(mst, pmax);
      float fac = exp2f(mst - mn);
      mst = mn; lst *= fac;
      float fj0 = __shfl(fac, r4+0), fj1 = __shfl(fac, r4+1);
      float fj2 = __shfl(fac, r4+2), fj3 = __shfl(fac, r4+3);
      for(int n=0;n<4;n++){
        o[n][0] *= fj0; o[n][1] *= fj1; o[n][2] *= fj2; o[n][3] *= fj3;
      }
    }
    float rs = 0.f;
    for(int n=0;n<4;n++){
      u16 w[4];
      for(int j=0;j<4;j++){
        float p = exp2f(s[n][j] - mst);
        rs += p;
        __bf16 pb = (__bf16)p;
        union { __bf16 b; u16 u; } cv; cv.b = pb;
        w[j] = cv.u;
      }
      *(s16x4*)&Ps[(wid*16 + lr)*64 + ((n*16 + r4) ^ rsw)] = *(s16x4*)w;
    }
    rs += __shfl_xor(rs,16); rs += __shfl_xor(rs,32);
    lst += rs;
    __builtin_amdgcn_s_setprio(1);
    for(int kc=0;kc<2;kc++){
      const int co = (kc*32 + g*8) ^ rsw;
      bf16x8 pf = *(const bf16x8*)&Ps[(wid*16 + lr)*64 + co];
      for(int n=0;n<4;n++){
        bf16x8 vf = *(const bf16x8*)&Vs[(n*16+lr)*64 + co];
        o[n] = __builtin_amdgcn_mfma_f32_16x16x32_bf16(pf, vf, o[n], 0,0,0);
      }
    }
    __builtin_amdgcn_s_setprio(0);
  }
  const long pr = (long)(qb*NCH + ci)*64;
  for(int n=0;n<4;n++)
    for(int j=0;j<4;j++)
      Op[(pr + wid*16 + r4 + j)*64 + n*16 + lr] = f2b(o[n][j]);
  if(lane < 16){
    Ml[(pr + wid*16 + lr)*2]     = mst;
    Ml[(pr + wid*16 + lr)*2 + 1] = lst;
  }
}

// ------------- flash attention REDUCE: merge 16 chunk partials per row ----
template<bool CAUSAL>
__global__ __launch_bounds__(256) void attn_red_k(const u16* __restrict__ Op,
                                                  const float* __restrict__ Ml,
                                                  u16* __restrict__ O){
  int r = blockIdx.x*4 + (threadIdx.x>>6);
  int d = threadIdx.x & 63;
  int qb = r >> 6, rt = r & 63;
  int nch = CAUSAL ? (qb>>3) + 1 : 16;
  long base = (long)qb*16*64 + rt;
  float m = -1e30f;
  for(int i=0;i<nch;i++) m = fmaxf(m, Ml[(base + i*64)*2]);
  float L = 0.f, acc = 0.f;
  for(int i=0;i<nch;i++){
    float mi = Ml[(base + i*64)*2], li = Ml[(base + i*64)*2 + 1];
    float w = exp2f(mi - m);
    L   += li * w;
    acc += w * b2f(Op[(base + i*64)*64 + d]);
  }
  O[(long)r*HD + d] = f2b(acc / L);
}

extern "C" void kernel_launch(void* const* d_in, const int* in_sizes, int n_in,
                              void* d_out, int out_size, void* d_ws, size_t ws_size,
                              hipStream_t stream){
  const float* enc  = (const float*)d_in[0];
  const float* prev = (const float*)d_in[1];
  const float* wq_m = (const float*)d_in[2];
  const float* wk_m = (const float*)d_in[3];
  const float* wv_m = (const float*)d_in[4];
  const float* wq_c = (const float*)d_in[5];
  const float* wk_c = (const float*)d_in[6];
  const float* wv_c = (const float*)d_in[7];
  const float* w_o  = (const float*)d_in[8];
  const float* ln_g = (const float*)d_in[9];
  const float* ln_b = (const float*)d_in[10];
  const float* w1   = (const float*)d_in[11];
  const float* b1   = (const float*)d_in[12];
  const float* w2   = (const float*)d_in[13];
  const float* b2   = (const float*)d_in[14];
  float* out = (float*)d_out;
  u16* ws  = (u16*)d_ws;

  // workspace layout (u16 element offsets) — total ≈ 76 MB (proven fit)
  u16* wq_m_t = ws;
  u16* wk_c_t = wq_m_t + 4*32768;
  u16* wost   = wq_m_t + 6*32768;
  u16* w1_t   = wost   + 32768;
  u16* w2_t   = w1_t   + 1048576;
  u16* enc_b  = w2_t   + 1048576;
  u16* prev_b = enc_b  + 4194304;
  u16* q_m    = prev_b + 4194304;
  u16* k_m    = q_m    + 524288;
  u16* v_m    = k_m    + 524288;
  u16* v_m_t  = v_m    + 524288;
  u16* head_m = v_m_t  + 524288;
  u16* k_c    = head_m + 524288;
  u16* v_c    = k_c    + 524288;
  u16* v_c_t  = v_c    + 524288;
  u16* q_c    = v_c_t  + 524288;
  u16* head_c = q_c    + 524288;
  u16* mmh    = head_c + 524288;
  u16* mh     = mmh    + 4194304;
  u16* xb     = mh     + 4194304;
  float* xf   = (float*)(xb + 4194304);
  u16* hbuf   = enc_b;                       // FFN mid (enc_b dead by then)
  u16* ffn    = mh;                          // mh dead by then
  u16* Op     = mmh;                         // bf16 partials (dead region)
  float* Ml   = (float*)(Op + (long)128*16*64*64);

  dim3 b256(256), tb(32,8);

  cvt2_k<<<dim3(2048,2), b256, 0, stream>>>(enc, prev, out, enc_b, prev_b, (long)SEQ*DM/8);

  // all weight prep in one launch (z: 0-5 proj^T, 6 w1^T, 7 w2^T, 8 wosum)
  prep_k<<<dim3(64,16,9), tb, 0, stream>>>(wq_m, wk_m, wv_m, wq_c, wk_c, wv_c,
                                           w1, w2, w_o, wq_m_t, w1_t, w2_t, wost);

  gemm2<64,64,0,true><<<dim3(SEQ/64,1,3), b256, 0, stream>>>(prev_b, wq_m_t, q_m, nullptr, HD, DM, 32768, 524288);
  gemm2<64,64,0,true><<<dim3(SEQ/64,1,2), b256, 0, stream>>>(enc_b,  wk_c_t, k_c, nullptr, HD, DM, 32768, 524288);
  vtrans2_k<<<dim3(2,256,2), tb, 0, stream>>>(v_m, v_m_t, v_c, v_c_t);

  attn_part_k<true><<<dim3(SEQ/64, 16), b256, 0, stream>>>(q_m, k_m, v_m_t, Op, Ml);
  attn_red_k<true><<<dim3(SEQ/4), b256, 0, stream>>>(Op, Ml, head_m);
  gemm2<64,128,0,false><<<dim3(SEQ/64,4,1), b256, 0, stream>>>(head_m, wost, mmh, nullptr, DM, HD, 0, 0);

  gemm2<64,64,0,false><<<dim3(SEQ/64,1,1), b256, 0, stream>>>(mmh, wq_m_t + 3*32768, q_c, nullptr, HD, DM, 0, 0);
  attn_part_k<false><<<dim3(SEQ/64, 16), b256, 0, stream>>>(q_c, k_c, v_c_t, Op, Ml);
  attn_red_k<false><<<dim3(SEQ/4), b256, 0, stream>>>(Op, Ml, head_c);
  gemm2<64,128,0,false><<<dim3(SEQ/64,4,1), b256, 0, stream>>>(head_c, wost, mh, nullptr, DM, HD, 0, 0);

  add_ln<true><<<dim3(SEQ/4), b256, 0, stream>>>(mh, prev, ln_g, ln_b, xf, xb);

  // FFN: single-buffer m97 structure
  gemm2<128,128,2,false><<<dim3(SEQ/128,HFF/128,1), b256, 0, stream>>>(xb, w1_t, hbuf, b1, HFF, DM, 0, 0);
  gemm2<64,128,1,false><<<dim3(SEQ/64,4,1),         b256, 0, stream>>>(hbuf, w2_t, ffn, b2, DM, HFF, 0, 0);

  add_ln<false><<<dim3(SEQ/4), b256, 0, stream>>>(ffn, xf, ln_g, ln_b, out + (long)SEQ*DM, nullptr);
}